// Round 5
// baseline (72.314 us; speedup 1.0000x reference)
//
#include <hip/hip_runtime.h>

// Conv2d 5x5, C=3, O=1, stride 1, pad 2, N=256, H=W=224, +bias.
// R5: fully-unrolled rolling walker.
//   R4 post-mortem: 70.9us vs 29us traffic floor; VALUBusy 52%, occ 37%.
//   The unroll-2 loop kept ring-shift movs + cur<-nxt copies + 64b addr
//   increments loop-carried (~60 extra VALU/step on top of 150 FMA).
// Fixes:
//   - FULL static unroll (18 steps): copies eliminated by renaming/copy-prop;
//     acc is a statically-indexed acc[SY] (<=5 live, born/retired per step).
//   - SY=14 (NSTRIP=16): 18 steps per 14 output rows (1.29x vs 1.5x halo),
//     grid = 1792 blocks = exactly 7 blocks/CU (uniform work).
//   - loads still issued one row ahead of consumption (prefetch order kept).
//   - NO launch_bounds min-waves arg (R2/R3: it forced VGPR=40 + mega-spill).

namespace {

constexpr int Hc = 224, Wc = 224, Cc = 3;
constexpr int HW = Hc * Wc;
constexpr int CHW = Cc * HW;
constexpr int TXv = 2;              // outputs per thread in x (float2)
constexpr int NCOL = Wc / TXv;      // 112
constexpr int SY = 14;              // strip height per thread
constexpr int NSTRIP = Hc / SY;     // 16
constexpr int BLK = 256;
constexpr int NSTEP = SY + 4;       // 18 input rows per strip

// Load one input row (3 ch x 3 aligned float2) or zeros if row outside image.
#define LOADROW(yi, dst)                                                      \
  do {                                                                        \
    if ((yi) >= 0 && (yi) < Hc) {                                             \
      const float* p_ = xb + (size_t)(yi) * Wc;                               \
      _Pragma("unroll") for (int c_ = 0; c_ < Cc; ++c_) {                     \
        const float* pc_ = p_ + c_ * HW;                                      \
        dst[c_][0] = *(const float2*)(pc_ + dA);                              \
        dst[c_][1] = *(const float2*)(pc_);                                   \
        dst[c_][2] = *(const float2*)(pc_ + dC);                              \
      }                                                                       \
    } else {                                                                  \
      _Pragma("unroll") for (int c_ = 0; c_ < Cc; ++c_) {                     \
        dst[c_][0] = make_float2(0.f, 0.f);                                   \
        dst[c_][1] = make_float2(0.f, 0.f);                                   \
        dst[c_][2] = make_float2(0.f, 0.f);                                   \
      }                                                                       \
    }                                                                         \
  } while (0)

__global__ __launch_bounds__(BLK) void conv5x5_full(
    const float* __restrict__ x, const float* __restrict__ wl,
    const float* __restrict__ bptr, float* __restrict__ out) {
  const int t = blockIdx.x * BLK + threadIdx.x;
  // decode: col fastest (coalescing), then strip (pow2), then n
  const int col = t % NCOL;
  const int rest = t / NCOL;
  const int strip = rest & (NSTRIP - 1);
  const int n = rest >> 4;            // NSTRIP = 16

  const int x0 = col * TXv;
  const int y0 = strip * SY;
  const bool lo = (x0 == 0);          // left image edge
  const bool hi = (x0 == Wc - TXv);   // right image edge

  // Weights: wave-uniform, compile-time offsets -> s_load (SGPRs).
  float w[Cc][5][5];
#pragma unroll
  for (int c = 0; c < Cc; ++c)
#pragma unroll
    for (int i = 0; i < 25; ++i) w[c][i / 5][i % 5] = wl[c * 25 + i];
  const float bias = bptr[0];

  const float* xb = x + (size_t)n * CHW + x0;
  float* ob = out + (size_t)n * HW + x0;

  // Aligned 8B loads at x0-2/x0/x0+2; edge lanes redirect the fully-masked
  // load inward (values zeroed at use) -> zero OOB accesses.
  const int dA = lo ? 0 : -2;
  const int dC = hi ? 0 : 2;

  float2 acc[SY];
#pragma unroll
  for (int o = 0; o < SY; ++o) acc[o] = make_float2(0.f, 0.f);

  float2 buf[2][Cc][3];               // double buffer; index static after unroll

  LOADROW(y0 - 2, buf[0]);

  // Input row s (yi = y0-2+s) feeds output rows o = s-ky, ky in [0,4].
  // acc[o] born at s=o, retired (stored) at s=o+4. All indices static.
#pragma unroll
  for (int s = 0; s < NSTEP; ++s) {
    const int yi = y0 - 2 + s;
    if (s + 1 < NSTEP) LOADROW(yi + 1, buf[(s + 1) & 1]);  // prefetch ahead

#pragma unroll
    for (int c = 0; c < Cc; ++c) {
      float win[6];
      win[0] = lo ? 0.f : buf[s & 1][c][0].x;
      win[1] = lo ? 0.f : buf[s & 1][c][0].y;
      win[2] = buf[s & 1][c][1].x;
      win[3] = buf[s & 1][c][1].y;
      win[4] = hi ? 0.f : buf[s & 1][c][2].x;
      win[5] = hi ? 0.f : buf[s & 1][c][2].y;
#pragma unroll
      for (int ky = 0; ky < 5; ++ky) {
        const int o = s - ky;
        if (o < 0 || o >= SY) continue;          // compile-time
#pragma unroll
        for (int kx = 0; kx < 5; ++kx) {
          acc[o].x = fmaf(win[kx], w[c][ky][kx], acc[o].x);
          acc[o].y = fmaf(win[kx + 1], w[c][ky][kx], acc[o].y);
        }
      }
    }

    if (s >= 4) {                                // output row s-4 complete
      float2 oo;
      oo.x = acc[s - 4].x + bias;
      oo.y = acc[s - 4].y + bias;
      *(float2*)(ob + (size_t)(y0 + s - 4) * Wc) = oo;
    }
  }
}

}  // namespace

extern "C" void kernel_launch(void* const* d_in, const int* in_sizes, int n_in,
                              void* d_out, int out_size, void* d_ws, size_t ws_size,
                              hipStream_t stream) {
  const float* x  = (const float*)d_in[0];   // [N,3,224,224] f32
  const float* wl = (const float*)d_in[1];   // [1,75] f32
  const float* b  = (const float*)d_in[2];   // [1] f32
  float* out = (float*)d_out;                // [N,224,224] f32

  const int N = out_size / HW;               // 256
  const int total = N * NSTRIP * NCOL;       // 458752
  const int nblk = total / BLK;              // 1792 = 7 per CU exactly

  conv5x5_full<<<nblk, BLK, 0, stream>>>(x, wl, b, out);
}

// Round 6
// 68.610 us; speedup vs baseline: 1.0540x; 1.0540x over previous
//
#include <hip/hip_runtime.h>

// Conv2d 5x5, C=3, O=1, stride 1, pad 2, N=256, H=W=224, +bias.
// R6: lean fully-unrolled walker.
//   R5 post-mortem: lean stream (VALU 53->42us) but VGPR 88 halved occupancy
//   -> net neutral. acc[] liveness is only 5 rows regardless of SY, so the
//   regs went to the explicit double-buffer + hoisted loads.
// Changes vs R5:
//   - no persistent buffer array: loads go straight into per-step window regs
//     (scheduler still hoists as deep as the reg budget allows)
//   - row-OOB handling only on the 4 boundary steps (y0-2,y0-1,y0+SY,y0+SY+1);
//     the 16 middle steps are guard-free straight-line code
//   - SY=16 (NSTRIP=14): halo 1.25x, grid 1568 = 6.1 blocks/CU
//   - NO launch_bounds min-waves arg (R2/R3: forced VGPR=40 -> mega-spill)

namespace {

constexpr int Hc = 224, Wc = 224, Cc = 3;
constexpr int HW = Hc * Wc;
constexpr int CHW = Cc * HW;
constexpr int TXv = 2;              // outputs per thread in x (float2)
constexpr int NCOL = Wc / TXv;      // 112
constexpr int SY = 16;              // strip height per thread
constexpr int NSTRIP = Hc / SY;     // 14
constexpr int BLK = 256;
constexpr int NSTEP = SY + 4;       // 20 input rows per strip

__global__ __launch_bounds__(BLK) void conv5x5_r6(
    const float* __restrict__ x, const float* __restrict__ wl,
    const float* __restrict__ bptr, float* __restrict__ out) {
  const int t = blockIdx.x * BLK + threadIdx.x;
  // decode: col fastest (coalescing), then strip, then n
  const int col = t % NCOL;
  const int rest = t / NCOL;
  const int strip = rest % NSTRIP;
  const int n = rest / NSTRIP;

  const int x0 = col * TXv;
  const int y0 = strip * SY;
  const bool lo = (col == 0);          // left image edge
  const bool hi = (col == NCOL - 1);   // right image edge

  // Weights: wave-uniform, compile-time offsets -> s_load (SGPRs).
  float w[Cc][5][5];
#pragma unroll
  for (int c = 0; c < Cc; ++c)
#pragma unroll
    for (int i = 0; i < 25; ++i) w[c][i / 5][i % 5] = wl[c * 25 + i];
  const float bias = bptr[0];

  const float* xb = x + (size_t)n * CHW + x0;
  float* ob = out + (size_t)n * HW + x0;

  // Aligned 8B loads at x0-2/x0/x0+2; edge lanes redirect the fully-masked
  // load inward (values zeroed in the window build) -> zero OOB accesses.
  const int dA = lo ? 0 : -2;
  const int dC = hi ? 0 : 2;

  float2 acc[SY];                      // statically indexed; <=5 live at once
#pragma unroll
  for (int o = 0; o < SY; ++o) acc[o] = make_float2(0.f, 0.f);

  // Input row s (yi = y0-2+s) feeds output rows o = s-ky, ky in [0,4].
  // acc[o]: born s=o, stored s=o+4. All indices compile-time after unroll.
#pragma unroll
  for (int s = 0; s < NSTEP; ++s) {
    const int yi = y0 + s - 2;
    // Only the first 2 / last 2 steps can leave the image: for s in [2,SY+1],
    // 0 <= y0+s-2 <= y0+SY-1 <= 223 always. `boundary` folds at compile time.
    const bool boundary = (s < 2) || (s >= SY + 2);

    bool rv = true;
    int yc = yi;
    if (boundary) {
      rv = (yi >= 0) && (yi < Hc);
      yc = yi < 0 ? 0 : (yi >= Hc ? Hc - 1 : yi);     // clamp address
    }

#pragma unroll
    for (int c = 0; c < Cc; ++c) {
      const float* pc = xb + (size_t)c * HW + (size_t)yc * Wc;
      float2 L = *(const float2*)(pc + dA);
      float2 M = *(const float2*)(pc);
      float2 R = *(const float2*)(pc + dC);
      if (boundary) {                 // per-lane cndmask, no divergence
        L.x = rv ? L.x : 0.f;  L.y = rv ? L.y : 0.f;
        M.x = rv ? M.x : 0.f;  M.y = rv ? M.y : 0.f;
        R.x = rv ? R.x : 0.f;  R.y = rv ? R.y : 0.f;
      }
      float win[6];
      win[0] = lo ? 0.f : L.x;
      win[1] = lo ? 0.f : L.y;
      win[2] = M.x;
      win[3] = M.y;
      win[4] = hi ? 0.f : R.x;
      win[5] = hi ? 0.f : R.y;
#pragma unroll
      for (int ky = 0; ky < 5; ++ky) {
        const int o = s - ky;
        if (o < 0 || o >= SY) continue;               // compile-time
#pragma unroll
        for (int kx = 0; kx < 5; ++kx) {
          acc[o].x = fmaf(win[kx], w[c][ky][kx], acc[o].x);
          acc[o].y = fmaf(win[kx + 1], w[c][ky][kx], acc[o].y);
        }
      }
    }

    if (s >= 4) {                     // output row s-4 complete
      float2 oo;
      oo.x = acc[s - 4].x + bias;
      oo.y = acc[s - 4].y + bias;
      *(float2*)(ob + (size_t)(y0 + s - 4) * Wc) = oo;
    }
  }
}

}  // namespace

extern "C" void kernel_launch(void* const* d_in, const int* in_sizes, int n_in,
                              void* d_out, int out_size, void* d_ws, size_t ws_size,
                              hipStream_t stream) {
  const float* x  = (const float*)d_in[0];   // [N,3,224,224] f32
  const float* wl = (const float*)d_in[1];   // [1,75] f32
  const float* b  = (const float*)d_in[2];   // [1] f32
  float* out = (float*)d_out;                // [N,224,224] f32

  const int N = out_size / HW;               // 256
  const int total = N * NSTRIP * NCOL;       // 401408
  const int nblk = total / BLK;              // 1568 blocks = 6.1 per CU

  conv5x5_r6<<<nblk, BLK, 0, stream>>>(x, wl, b, out);
}

// Round 7
// 55.452 us; speedup vs baseline: 1.3041x; 1.2373x over previous
//
#include <hip/hip_runtime.h>

// Conv2d 5x5, C=3, O=1, stride 1, pad 2, N=256, H=W=224, +bias.
// R7: float4-wide walker (TXv=4) + grid that fills residency.
//   R6 post-mortem: VALU busy ~34us + stalls ~34us; grid supplied only 24.5
//   waves/CU (avg occ 48%); VGPR 36 = shallow per-wave MLP.
// Changes:
//   - TXv=4: 9 loads/step serve 4 outputs (addr+select+load overhead per
//     output halves; FMA/output fixed at 75). Loads at x0-4/x0/x0+4, all
//     16B aligned; window uses L.zw|M|R.xy = win[0..7].
//   - SY=7, NSTRIP=32: 1792 blocks = exactly 7 blocks/CU = 28 waves/CU.
//   - full unroll, boundary-only row guards (s in {0,1,9,10}), no
//     launch_bounds min-arg (R2/R3: forced spill).

namespace {

constexpr int Hc = 224, Wc = 224, Cc = 3;
constexpr int HW = Hc * Wc;
constexpr int CHW = Cc * HW;
constexpr int TXv = 4;              // outputs per thread in x (float4)
constexpr int NCOL = Wc / TXv;      // 56
constexpr int SY = 7;               // strip height per thread
constexpr int NSTRIP = Hc / SY;     // 32
constexpr int BLK = 256;
constexpr int NSTEP = SY + 4;       // 11 input rows per strip

__global__ __launch_bounds__(BLK) void conv5x5_r7(
    const float* __restrict__ x, const float* __restrict__ wl,
    const float* __restrict__ bptr, float* __restrict__ out) {
  const int t = blockIdx.x * BLK + threadIdx.x;
  // decode: col fastest (coalescing), then strip (pow2), then n
  const int col = t % NCOL;
  const int rest = t / NCOL;
  const int strip = rest & (NSTRIP - 1);
  const int n = rest >> 5;            // NSTRIP = 32

  const int x0 = col * TXv;
  const int y0 = strip * SY;
  const bool lo = (col == 0);          // left image edge lane
  const bool hi = (col == NCOL - 1);   // right image edge lane

  // Weights: wave-uniform, compile-time offsets -> s_load (SGPRs).
  float w[Cc][5][5];
#pragma unroll
  for (int c = 0; c < Cc; ++c)
#pragma unroll
    for (int i = 0; i < 25; ++i) w[c][i / 5][i % 5] = wl[c * 25 + i];
  const float bias = bptr[0];

  const float* xb = x + (size_t)n * CHW + x0;
  float* ob = out + (size_t)n * HW + x0;

  // 16B-aligned loads at x0-4 / x0 / x0+4; edge lanes redirect the masked
  // load inward (values zeroed in window build) -> zero OOB accesses.
  const int dL = lo ? 0 : -4;
  const int dR = hi ? 0 : 4;

  float4 acc[SY];                      // statically indexed; <=5 live at once
#pragma unroll
  for (int o = 0; o < SY; ++o) acc[o] = make_float4(0.f, 0.f, 0.f, 0.f);

  // Input row s (yi = y0-2+s) feeds output rows o = s-ky, ky in [0,4].
  // acc[o]: born s=o, stored s=o+4. All indices compile-time after unroll.
#pragma unroll
  for (int s = 0; s < NSTEP; ++s) {
    const int yi = y0 + s - 2;
    // Middle steps s in [2, SY+1]: 0 <= yi <= y0+SY-1 <= 223 always.
    const bool boundary = (s < 2) || (s >= SY + 2);

    bool rv = true;
    int yc = yi;
    if (boundary) {
      rv = (yi >= 0) && (yi < Hc);
      yc = yi < 0 ? 0 : (yi >= Hc ? Hc - 1 : yi);     // clamp address
    }

    // Issue all 9 loads for this step up front (batched MLP).
    float4 L[Cc], M[Cc], R[Cc];
#pragma unroll
    for (int c = 0; c < Cc; ++c) {
      const float* pc = xb + (size_t)c * HW + (size_t)yc * Wc;
      L[c] = *(const float4*)(pc + dL);
      M[c] = *(const float4*)(pc);
      R[c] = *(const float4*)(pc + dR);
    }

#pragma unroll
    for (int c = 0; c < Cc; ++c) {
      // win[j] = x[x0-2+j], j=0..7 (outputs need [x0-2, x0+5])
      float win[8];
      win[0] = (lo || (boundary && !rv)) ? 0.f : L[c].z;
      win[1] = (lo || (boundary && !rv)) ? 0.f : L[c].w;
      win[2] = (boundary && !rv) ? 0.f : M[c].x;
      win[3] = (boundary && !rv) ? 0.f : M[c].y;
      win[4] = (boundary && !rv) ? 0.f : M[c].z;
      win[5] = (boundary && !rv) ? 0.f : M[c].w;
      win[6] = (hi || (boundary && !rv)) ? 0.f : R[c].x;
      win[7] = (hi || (boundary && !rv)) ? 0.f : R[c].y;
#pragma unroll
      for (int ky = 0; ky < 5; ++ky) {
        const int o = s - ky;
        if (o < 0 || o >= SY) continue;               // compile-time
#pragma unroll
        for (int kx = 0; kx < 5; ++kx) {
          const float wv = w[c][ky][kx];
          acc[o].x = fmaf(win[kx + 0], wv, acc[o].x);
          acc[o].y = fmaf(win[kx + 1], wv, acc[o].y);
          acc[o].z = fmaf(win[kx + 2], wv, acc[o].z);
          acc[o].w = fmaf(win[kx + 3], wv, acc[o].w);
        }
      }
    }

    if (s >= 4) {                     // output row s-4 complete
      float4 oo;
      oo.x = acc[s - 4].x + bias;
      oo.y = acc[s - 4].y + bias;
      oo.z = acc[s - 4].z + bias;
      oo.w = acc[s - 4].w + bias;
      *(float4*)(ob + (size_t)(y0 + s - 4) * Wc) = oo;
    }
  }
}

}  // namespace

extern "C" void kernel_launch(void* const* d_in, const int* in_sizes, int n_in,
                              void* d_out, int out_size, void* d_ws, size_t ws_size,
                              hipStream_t stream) {
  const float* x  = (const float*)d_in[0];   // [N,3,224,224] f32
  const float* wl = (const float*)d_in[1];   // [1,75] f32
  const float* b  = (const float*)d_in[2];   // [1] f32
  float* out = (float*)d_out;                // [N,224,224] f32

  const int N = out_size / HW;               // 256
  const int total = N * NSTRIP * NCOL;       // 458752
  const int nblk = total / BLK;              // 1792 = exactly 7 blocks/CU

  conv5x5_r7<<<nblk, BLK, 0, stream>>>(x, wl, b, out);
}